// Round 1
// baseline (2064.303 us; speedup 1.0000x reference)
//
#include <hip/hip_runtime.h>

#define TB 256
#define NB 512
#define HW 28
#define NPIX 784
#define NELEM 12544   // 16*28*28
#define EPT 49        // NELEM / TB
#define NPOOL 3136    // 16*14*14
#define TT 8
#define NFC 100
#define NOUT 10

#define LDS_ADD(p, v) __hip_atomic_fetch_add((p), (v), __ATOMIC_RELAXED, __HIP_MEMORY_SCOPE_WORKGROUP)
#define GLB_ADD(p, v) __hip_atomic_fetch_add((p), (v), __ATOMIC_RELAXED, __HIP_MEMORY_SCOPE_AGENT)

// ---------------------------------------------------------------------------
// init: zero the firing-rate accumulator [T][4]
__global__ void snn_init(float* fr_g) {
    if (threadIdx.x < 32) fr_g[threadIdx.x] = 0.f;
}

// one-time transpose w_fc1 [100][3136] -> wT [3136][100]
__global__ void snn_transpose(const float* __restrict__ w, float* __restrict__ wT) {
    int i = blockIdx.x * TB + threadIdx.x;
    if (i < NFC * NPOOL) {
        int row = i / NPOOL;   // 0..99
        int col = i % NPOOL;   // 0..3135
        wT[col * NFC + row] = w[i];
    }
}

// ---------------------------------------------------------------------------
// main: one block per image, full T-loop fused.
__global__ __launch_bounds__(TB, 2)
void snn_main(const float* __restrict__ xg, const float* __restrict__ w_sconv,
              const float* __restrict__ w_conv, const float* __restrict__ w_fc1,
              const float* __restrict__ w_fc2, const float* __restrict__ wT,
              float* __restrict__ out, float* __restrict__ fr_g, int useT)
{
    __shared__ float v2[NELEM];              // layout: (y*28+x)*16 + co
    __shared__ float wc[2304];               // [ci][ky][kx][co]
    __shared__ unsigned short lst[1024];     // spike-chunk list
    __shared__ unsigned int pooled_bits[98]; // 3136 bits, idx co*196+py*14+px
    __shared__ unsigned int pf_bits[98];
    __shared__ float s3v[NFC];
    __shared__ int lst_n;

    const int tid = threadIdx.x;
    const int b = blockIdx.x;

    // ---- stage x image + w_sconv (aliased over v2, which is init'd later)
    float* ximg = v2;
    float* wsc = v2 + NPIX;
    for (int i = tid; i < NPIX; i += TB) ximg[i] = xg[b * NPIX + i];
    for (int i = tid; i < 144; i += TB) wsc[i] = w_sconv[i];
    for (int i = tid; i < 2304; i += TB) {
        int co = i / 144, r = i % 144;       // r = ci*9 + ky*3 + kx
        wc[r * 16 + co] = w_conv[i];
    }
    __syncthreads();

    // ---- xs = conv3x3(x, w_sconv), kept in registers (mapping g = e*TB+tid,
    //      ci = g&15, s = g>>4, y = s/28, x = s%28)
    float xs[EPT], v1[EPT];
#pragma unroll
    for (int e = 0; e < EPT; e++) {
        int g = e * TB + tid;
        int ci = g & 15, s = g >> 4;
        int yy = s / HW, xx = s % HW;
        float acc = 0.f;
#pragma unroll
        for (int ky = 0; ky < 3; ky++) {
            int ys = yy + ky - 1;
            if (ys < 0 || ys >= HW) continue;
#pragma unroll
            for (int kx = 0; kx < 3; kx++) {
                int xsrc = xx + kx - 1;
                if (xsrc < 0 || xsrc >= HW) continue;
                acc = fmaf(wsc[ci * 9 + ky * 3 + kx], ximg[ys * HW + xsrc], acc);
            }
        }
        xs[e] = acc;
        v1[e] = 0.f;
    }
    __syncthreads();

    for (int i = tid; i < NELEM; i += TB) v2[i] = 0.f;
    for (int i = tid; i < 98; i += TB) { pooled_bits[i] = 0u; pf_bits[i] = 0u; }
    if (tid == 0) lst_n = 0;
    __syncthreads();

    float vfc = 0.f;                 // thread tid<100 owns vfc[tid]
    float vout = 0.f, cnt4 = 0.f, lat = 0.f;  // thread tid<10 owns out neuron tid

    for (int t = 0; t < TT; t++) {
        int c1 = 0, c2 = 0, c3 = 0, c4 = 0;

        // ===== layer 1: one-spike IF + spike-driven conv scatter into v2 ====
#pragma unroll
        for (int e = 0; e < EPT; e++) {
            v1[e] += xs[e];
            if (v1[e] >= 1.0f) {
                v1[e] = -1e30f;      // fired: absorb all future input
                c1++;
                int idx = atomicAdd(&lst_n, 1);
                lst[idx] = (unsigned short)(e * TB + tid);
            }
            if ((e & 3) == 3 || e == EPT - 1) {   // flush every 4 sub-rounds (<=1024 spikes)
                __syncthreads();
                const int n16 = lst_n * 16;
                for (int k = tid; k < n16; k += TB) {
                    const int co = k & 15;
                    const int g = lst[k >> 4];
                    const int ci = g & 15, s = g >> 4;
                    const int sy = s / HW, sx = s % HW;
                    const int base = s * 16 + co;
                    const int wb = ci * 144 + co;
                    const bool yu = (sy < HW - 1), yd = (sy > 0);
                    const bool xu = (sx < HW - 1), xd = (sx > 0);
                    if (yu && xu) LDS_ADD(&v2[base + (HW + 1) * 16], wc[wb]);
                    if (yu)       LDS_ADD(&v2[base + (HW    ) * 16], wc[wb + 16]);
                    if (yu && xd) LDS_ADD(&v2[base + (HW - 1) * 16], wc[wb + 32]);
                    if (xu)       LDS_ADD(&v2[base + 16           ], wc[wb + 48]);
                                  LDS_ADD(&v2[base               ], wc[wb + 64]);
                    if (xd)       LDS_ADD(&v2[base - 16           ], wc[wb + 80]);
                    if (yd && xu) LDS_ADD(&v2[base - (HW - 1) * 16], wc[wb + 96]);
                    if (yd)       LDS_ADD(&v2[base - (HW    ) * 16], wc[wb + 112]);
                    if (yd && xd) LDS_ADD(&v2[base - (HW + 1) * 16], wc[wb + 128]);
                }
                __syncthreads();
                if (tid == 0) lst_n = 0;
                __syncthreads();
            }
        }

        // ===== layer 2: one-spike IF + maxpool spike bits =====
        for (int i = tid; i < NELEM; i += TB) {
            float v = v2[i];
            if (v >= 1.0f) {
                v2[i] = -1e30f;
                c2++;
                int s = i >> 4, co = i & 15;
                int py = (s / HW) >> 1, px = (s % HW) >> 1;
                int pp = co * 196 + py * 14 + px;
                atomicOr(&pooled_bits[pp >> 5], 1u << (pp & 31));
            }
        }
        __syncthreads();

        // ===== first-spike pool -> incremental FC1 accumulation =====
        for (int it = 0; it < 13; it++) {
            int pp = it * TB + tid;
            if (pp < NPOOL) {
                unsigned int m = 1u << (pp & 31);
                if ((pooled_bits[pp >> 5] & m) && !(pf_bits[pp >> 5] & m)) {
                    atomicOr(&pf_bits[pp >> 5], m);
                    int idx = atomicAdd(&lst_n, 1);
                    lst[idx] = (unsigned short)pp;
                }
            }
            if ((it & 3) == 3 || it == 12) {
                __syncthreads();
                const int n = lst_n;
                if (tid < NFC) {
                    if (useT) {
                        for (int j = 0; j < n; j++)
                            vfc += wT[(int)lst[j] * NFC + tid];
                    } else {
                        for (int j = 0; j < n; j++)
                            vfc += w_fc1[tid * NPOOL + (int)lst[j]];
                    }
                }
                __syncthreads();
                if (tid == 0) lst_n = 0;
                __syncthreads();
            }
        }

        // ===== FC one-spike IF =====
        if (tid < NFC) {
            float s3 = 0.f;
            if (vfc >= 1.0f) { vfc = -1e30f; s3 = 1.f; c3 = 1; }
            s3v[tid] = s3;
        }
        __syncthreads();

        // ===== FC2 + readout IF (fires repeatedly, hard reset to 0) =====
        if (tid < NOUT) {
            float o = 0.f;
            for (int i = 0; i < NFC; i++)
                o = fmaf(s3v[i], w_fc2[tid * NFC + i], o);
            vout += o;
            if (vout >= 1.0f) { vout = 0.f; c4 = 1; cnt4 += 1.f; }
            if (cnt4 >= 0.5f) lat += 1.f;   // heaviside(counter_t - 0.5)
        }

        // ===== firing-rate accumulation (wave reduce + global atomics) =====
        int pa = c1 | (c2 << 16);            // per-wave sums stay < 2^16 per field
        int pb = c3 | (c4 << 16);
#pragma unroll
        for (int off = 32; off > 0; off >>= 1) {
            pa += __shfl_xor(pa, off, 64);
            pb += __shfl_xor(pb, off, 64);
        }
        if ((tid & 63) == 0) {
            GLB_ADD(&fr_g[t * 4 + 0], (float)(pa & 0xffff));
            GLB_ADD(&fr_g[t * 4 + 1], (float)((unsigned)pa >> 16));
            GLB_ADD(&fr_g[t * 4 + 2], (float)(pb & 0xffff));
            GLB_ADD(&fr_g[t * 4 + 3], (float)((unsigned)pb >> 16));
        }

        __syncthreads();
        for (int i = tid; i < 98; i += TB) pooled_bits[i] = 0u;
        __syncthreads();
    }

    if (tid < NOUT) out[b * NOUT + tid] = lat * 0.125f;
}

// ---------------------------------------------------------------------------
// finalize: reg_loss = sum_l max_t fr[t][l]/size_l  ->  out[5120]
__global__ void snn_finalize(const float* __restrict__ fr_g, float* __restrict__ out) {
    if (threadIdx.x == 0) {
        const float inv0 = 1.f / 6422528.f;  // B*16*28*28
        const float inv2 = 1.f / 51200.f;    // B*100
        const float inv3 = 1.f / 5120.f;     // B*10
        const float invs[4] = { inv0, inv0, inv2, inv3 };
        float reg = 0.f;
        for (int l = 0; l < 4; l++) {
            float mx = -INFINITY;
            for (int t = 0; t < TT; t++)
                mx = fmaxf(mx, fr_g[t * 4 + l] * invs[l]);
            reg += mx;
        }
        out[NB * NOUT] = reg;
    }
}

// ---------------------------------------------------------------------------
extern "C" void kernel_launch(void* const* d_in, const int* in_sizes, int n_in,
                              void* d_out, int out_size, void* d_ws, size_t ws_size,
                              hipStream_t stream) {
    const float* x       = (const float*)d_in[0];
    const float* w_sconv = (const float*)d_in[1];
    const float* w_conv  = (const float*)d_in[2];
    const float* w_fc1   = (const float*)d_in[3];
    const float* w_fc2   = (const float*)d_in[4];
    float* out = (float*)d_out;

    const size_t needT = (size_t)NFC * NPOOL * sizeof(float) + 128;
    int useT = (ws_size >= needT) ? 1 : 0;
    float* wT   = (float*)d_ws;
    float* fr_g = useT ? (wT + NFC * NPOOL) : (float*)d_ws;

    snn_init<<<1, 64, 0, stream>>>(fr_g);
    if (useT)
        snn_transpose<<<(NFC * NPOOL + TB - 1) / TB, TB, 0, stream>>>(w_fc1, wT);
    snn_main<<<NB, TB, 0, stream>>>(x, w_sconv, w_conv, w_fc1, w_fc2, wT, out, fr_g, useT);
    snn_finalize<<<1, 64, 0, stream>>>(fr_g, out);
}

// Round 2
// 1936.025 us; speedup vs baseline: 1.0663x; 1.0663x over previous
//
#include <hip/hip_runtime.h>

#define TB 256
#define NIMG 512
#define HW 28
#define NPIX 784
#define NELEM 12544     // 16 ci * 784 inputs per image
#define EPT 49          // NELEM / TB
#define NOUTN 3136      // per-block outputs: 4 co * 784
#define NPOOLB 784      // per-block pool windows: 4 co * 196
#define TT 8
#define NFC 100
#define NOUT 10

// workspace layout (in floats)
#define WT_FLOATS 313600            // wT: 3136 x 100
#define VFCB_FLOATS 409600          // vfc buckets: 512 x 8 x 100
#define FR_OFF (WT_FLOATS + VFCB_FLOATS)

#define LDS_ADD(p, v) __hip_atomic_fetch_add((p), (v), __ATOMIC_RELAXED, __HIP_MEMORY_SCOPE_WORKGROUP)
#define GLB_ADD(p, v) __hip_atomic_fetch_add((p), (v), __ATOMIC_RELAXED, __HIP_MEMORY_SCOPE_AGENT)

// ---------------------------------------------------------------------------
__global__ void snn_init(float* ws) {
    int idx = blockIdx.x * TB + threadIdx.x;
    if (idx < VFCB_FLOATS) ws[WT_FLOATS + idx] = 0.f;
    if (idx < 32) ws[FR_OFF + idx] = 0.f;
}

// w_fc1 [100][3136] -> wT [3136][100] (coalesced column reads)
__global__ void snn_transpose(const float* __restrict__ w, float* __restrict__ wT) {
    int i = blockIdx.x * TB + threadIdx.x;
    if (i < NFC * 3136) {
        int row = i / 3136, col = i % 3136;
        wT[col * NFC + row] = w[i];
    }
}

// ---------------------------------------------------------------------------
// One block per (image, co-quad). Computes layer-1 first-spike times in
// closed form (registers), scatters spike-driven conv into v2 (4 co's),
// finds layer-2 first-spike times, pools (min), and accumulates FC1 buckets.
__global__ __launch_bounds__(TB)
void snn_ab(const float* __restrict__ xg, const float* __restrict__ w_sconv,
            const float* __restrict__ w_conv, const float* __restrict__ wT,
            float* __restrict__ vfcb, float* __restrict__ fr_g)
{
    __shared__ float v2[NOUTN];                 // [pos*4 + c]
    __shared__ float wc[576];                   // [(ci*9+k)*4 + c]
    __shared__ float facb[8 * TB];              // per-thread FC1 buckets [k][tid]
    __shared__ unsigned short lst[NELEM] __attribute__((aligned(16)));
    __shared__ unsigned char t2m[NOUTN];        // layer-2 first-spike time (8 = never)
    __shared__ unsigned char tq[NPOOLB];        // pooled first-spike time
    __shared__ int hist1[8], hist2[8];
    __shared__ int lst_n;

    const int tid = threadIdx.x;
    const int b = blockIdx.x >> 2;
    const int coq = blockIdx.x & 3;

    float* xst = (float*)lst;                   // alias: x image (784 f)
    float* wsc = xst + NPIX;                    // alias: w_sconv (144 f)

    // ---- setup
    for (int i2 = tid; i2 < NPIX; i2 += TB) xst[i2] = xg[b * NPIX + i2];
    for (int i2 = tid; i2 < 144; i2 += TB) wsc[i2] = w_sconv[i2];
    for (int i2 = tid; i2 < 576; i2 += TB) {
        int c = i2 & 3, r = i2 >> 2;            // r = ci*9 + k
        wc[i2] = w_conv[(coq * 4 + c) * 144 + r];
    }
    for (int i2 = tid; i2 < NOUTN; i2 += TB) { v2[i2] = 0.f; t2m[i2] = 8; }
    for (int i2 = tid; i2 < 8 * TB; i2 += TB) facb[i2] = 0.f;
    if (tid < 8) { hist1[tid] = 0; hist2[tid] = 0; }
    if (tid == 0) lst_n = 0;
    __syncthreads();

    // ---- phase A: xs conv + closed-form t1, packed 4 bits/input in regs
    unsigned int rr[7] = {0, 0, 0, 0, 0, 0, 0};
#pragma unroll
    for (int e = 0; e < EPT; e++) {
        int g = e * TB + tid;
        int ci = g & 15, s = g >> 4;
        int yy = s / HW, xx = s % HW;
        float acc = 0.f;
#pragma unroll
        for (int ky = 0; ky < 3; ky++) {
            int ys = yy + ky - 1;
            if (ys < 0 || ys >= HW) continue;
#pragma unroll
            for (int kx = 0; kx < 3; kx++) {
                int xsrc = xx + kx - 1;
                if (xsrc < 0 || xsrc >= HW) continue;
                acc = fmaf(wsc[ci * 9 + ky * 3 + kx], xst[ys * HW + xsrc], acc);
            }
        }
        int t1 = 8; float v = 0.f;
#pragma unroll
        for (int t = 0; t < TT; t++) {          // exact reference add order
            v += acc;
            if (t1 == 8 && v >= 1.0f) t1 = t;
        }
        rr[e >> 3] |= (unsigned)t1 << ((e & 7) * 4);
        if (coq == 0 && t1 < 8) atomicAdd(&hist1[t1], 1);
    }
    __syncthreads();                            // xst/wsc alias dies here

    // ---- 8 phases: append fired inputs -> scatter conv -> check crossings
    for (int t = 0; t < TT; t++) {
#pragma unroll
        for (int e = 0; e < EPT; e++) {
            int t1e = (rr[e >> 3] >> ((e & 7) * 4)) & 15;
            if (t1e == t) {
                int idx = atomicAdd(&lst_n, 1);
                lst[idx] = (unsigned short)(e * TB + tid);
            }
        }
        __syncthreads();
        const int total = lst_n * 9;
        for (int idx = tid; idx < total; idx += TB) {
            int item = idx / 9;
            int k = idx - item * 9;
            int g = lst[item];
            int ci = g & 15, pos = g >> 4;
            int sy = pos / HW, sx = pos - sy * HW;
            int ky = k / 3, kx = k - ky * 3;
            int oy = sy + 1 - ky, ox = sx + 1 - kx;
            if ((unsigned)oy < HW && (unsigned)ox < HW) {
                int ob = (oy * HW + ox) * 4;
                int wb = (ci * 9 + k) * 4;
                float4 w4 = *reinterpret_cast<const float4*>(&wc[wb]);
                LDS_ADD(&v2[ob + 0], w4.x);
                LDS_ADD(&v2[ob + 1], w4.y);
                LDS_ADD(&v2[ob + 2], w4.z);
                LDS_ADD(&v2[ob + 3], w4.w);
            }
        }
        __syncthreads();
        int c2 = 0;
        for (int lin = tid; lin < NOUTN; lin += TB) {
            if (t2m[lin] == 8 && v2[lin] >= 1.0f) { t2m[lin] = (unsigned char)t; c2++; }
        }
        if (c2) atomicAdd(&hist2[t], c2);
        if (tid == 0) lst_n = 0;
        __syncthreads();
    }

    // ---- first-spike pool: tq = min over 2x2 window of t2
    for (int u = tid; u < NPOOLB; u += TB) {    // u = c*196 + py*14 + px
        int c = u / 196, rem = u - c * 196;
        int py = rem / 14, px = rem - py * 14;
        int base = ((py * 2) * HW + px * 2) * 4 + c;
        int m0 = t2m[base], m1 = t2m[base + 4];
        int m2 = t2m[base + HW * 4], m3 = t2m[base + HW * 4 + 4];
        tq[u] = (unsigned char)min(min(m0, m1), min(m2, m3));
    }
    __syncthreads();

    // ---- FC1 bucket accumulation: facb[tq[p]][tid] += wT[p][i]
    const int h = tid >> 7;                     // p-half
    const int i = tid & 127;                    // fc neuron (active < 100)
    const float* wp = wT + (size_t)(coq * 784 + h * 392) * NFC + i;
    for (int pp = 0; pp < 392; pp++) {
        int tv = tq[h * 392 + pp];              // wave-uniform (LDS broadcast)
        if (tv < 8) {
            if (i < NFC) facb[tv * TB + tid] += *wp;   // private slot, conflict-free
        }
        wp += NFC;
    }
    if (i < NFC) {
#pragma unroll
        for (int k = 0; k < 8; k++)
            GLB_ADD(&vfcb[((size_t)b * 8 + k) * NFC + i], facb[k * TB + tid]);
    }

    if (tid < 8) {
        if (coq == 0) GLB_ADD(&fr_g[tid * 4 + 0], (float)hist1[tid]);
        GLB_ADD(&fr_g[tid * 4 + 1], (float)hist2[tid]);
    }
}

// ---------------------------------------------------------------------------
// Per-image: FC1 prefix -> t3, FC2 buckets, readout IF sim, latency score.
__global__ void snn_d(const float* __restrict__ vfcb, const float* __restrict__ w_fc2,
                      float* __restrict__ out, float* __restrict__ fr_g)
{
    __shared__ unsigned char t3L[NFC];
    __shared__ int hist3[8], hist4[8];
    const int tid = threadIdx.x;
    const int b = blockIdx.x;
    if (tid < 8) { hist3[tid] = 0; hist4[tid] = 0; }
    __syncthreads();
    if (tid < NFC) {
        float v = 0.f; int t3 = 8;
#pragma unroll
        for (int k = 0; k < TT; k++) {
            v += vfcb[((size_t)b * 8 + k) * NFC + tid];
            if (t3 == 8 && v >= 1.0f) t3 = k;
        }
        t3L[tid] = (unsigned char)t3;
        if (t3 < 8) atomicAdd(&hist3[t3], 1);
    }
    __syncthreads();
    if (tid < NOUT) {
        float acc[8] = {0, 0, 0, 0, 0, 0, 0, 0};
        for (int i2 = 0; i2 < NFC; i2++) {
            int tv = t3L[i2];                   // wave-uniform broadcast
            if (tv < 8) {
                float w = w_fc2[tid * NFC + i2];
#pragma unroll
                for (int k = 0; k < 8; k++) acc[k] += (tv == k) ? w : 0.f;
            }
        }
        float vout = 0.f; int cnt = 0; float lat = 0.f;
#pragma unroll
        for (int t = 0; t < TT; t++) {
            vout += acc[t];
            if (vout >= 1.0f) { vout = 0.f; cnt++; atomicAdd(&hist4[t], 1); }
            if (cnt >= 1) lat += 1.f;
        }
        out[b * NOUT + tid] = lat * 0.125f;
    }
    __syncthreads();
    if (tid < 8) {
        GLB_ADD(&fr_g[tid * 4 + 2], (float)hist3[tid]);
        GLB_ADD(&fr_g[tid * 4 + 3], (float)hist4[tid]);
    }
}

// ---------------------------------------------------------------------------
__global__ void snn_finalize(const float* __restrict__ fr_g, float* __restrict__ out) {
    if (threadIdx.x == 0) {
        const float inv0 = 1.f / 6422528.f;   // B*16*28*28
        const float inv2 = 1.f / 51200.f;     // B*100
        const float inv3 = 1.f / 5120.f;      // B*10
        const float invs[4] = { inv0, inv0, inv2, inv3 };
        float reg = 0.f;
        for (int l = 0; l < 4; l++) {
            float mx = -INFINITY;
            for (int t = 0; t < TT; t++)
                mx = fmaxf(mx, fr_g[t * 4 + l] * invs[l]);
            reg += mx;
        }
        out[NIMG * NOUT] = reg;
    }
}

// ---------------------------------------------------------------------------
extern "C" void kernel_launch(void* const* d_in, const int* in_sizes, int n_in,
                              void* d_out, int out_size, void* d_ws, size_t ws_size,
                              hipStream_t stream) {
    const float* x       = (const float*)d_in[0];
    const float* w_sconv = (const float*)d_in[1];
    const float* w_conv  = (const float*)d_in[2];
    const float* w_fc1   = (const float*)d_in[3];
    const float* w_fc2   = (const float*)d_in[4];
    float* out = (float*)d_out;

    float* ws   = (float*)d_ws;
    float* wT   = ws;
    float* vfcb = ws + WT_FLOATS;
    float* fr_g = ws + FR_OFF;

    snn_init<<<1600, TB, 0, stream>>>(ws);
    snn_transpose<<<1225, TB, 0, stream>>>(w_fc1, wT);
    snn_ab<<<NIMG * 4, TB, 0, stream>>>(x, w_sconv, w_conv, wT, vfcb, fr_g);
    snn_d<<<NIMG, 128, 0, stream>>>(vfcb, w_fc2, out, fr_g);
    snn_finalize<<<1, 64, 0, stream>>>(fr_g, out);
}

// Round 3
// 305.590 us; speedup vs baseline: 6.7551x; 6.3354x over previous
//
#include <hip/hip_runtime.h>

#define TB 256
#define NIMG 512
#define HW 28
#define NPIX 784
#define TT 8
#define NFC 100
#define NOUT 10

// workspace layout (floats)
#define WT_FLOATS 313600            // wT: 3136 x 100
#define VFCB_FLOATS 409600          // vfc buckets: 512 x 8 x 100
#define FR_OFF (WT_FLOATS + VFCB_FLOATS)

#define GLB_ADD(p, v) __hip_atomic_fetch_add((p), (v), __ATOMIC_RELAXED, __HIP_MEMORY_SCOPE_AGENT)

// ---------------------------------------------------------------------------
__global__ void snn_init(float* ws) {
    int idx = blockIdx.x * TB + threadIdx.x;
    if (idx < VFCB_FLOATS) ws[WT_FLOATS + idx] = 0.f;
    if (idx < 32) ws[FR_OFF + idx] = 0.f;
}

// w_fc1 [100][3136] -> wT [3136][100]
__global__ void snn_transpose(const float* __restrict__ w, float* __restrict__ wT) {
    int i = blockIdx.x * TB + threadIdx.x;
    if (i < NFC * 3136) {
        int row = i / 3136, col = i % 3136;
        wT[col * NFC + row] = w[i];
    }
}

// ---------------------------------------------------------------------------
// One block per (image, co-half). Phase A: closed-form layer-1 spike times ->
// per-phase fired bitmasks (one atomicOr per spike, no readback). Then a
// barrier-free register-resident gather computes layer-2 first-spike times,
// pooling, and FC1 bucket accumulation.
__global__ __launch_bounds__(TB, 4)
void snn_main(const float* __restrict__ xg, const float* __restrict__ w_sconv,
              const float* __restrict__ w_conv, const float* __restrict__ wT,
              float* __restrict__ vfcb, float* __restrict__ fr_g)
{
    __shared__ float xst[NPIX];
    __shared__ float wsc[144];
    __shared__ float wc[1152];               // [(ci*9+k)*8 + c], c = local co 0..7
    __shared__ unsigned int mask32[TT * 392];// ushort view: [t][784] of 16 ci bits
    __shared__ unsigned int t2w[NPIX];       // per position: 8 co x 4-bit t2 code
    __shared__ unsigned char tq[1568];       // pooled first-spike time, u = c*196+wy*14+wx
    __shared__ float facb[TT * TB];          // FC1 buckets, slot [t][tid] (private)
    __shared__ int hist1[TT], hist2[TT];

    const int tid = threadIdx.x;
    const int b = blockIdx.x >> 1;
    const int half = blockIdx.x & 1;
    const int co0 = half * 8;

    // ---- stage
    for (int i = tid; i < NPIX; i += TB) xst[i] = xg[b * NPIX + i];
    for (int i = tid; i < 144; i += TB) wsc[i] = w_sconv[i];
    for (int i = tid; i < 1152; i += TB) {
        int c = i & 7, r = i >> 3;           // r = ci*9 + k
        wc[i] = w_conv[(co0 + c) * 144 + r];
    }
    for (int i = tid; i < TT * 392; i += TB) mask32[i] = 0u;
    if (tid < TT) { hist1[tid] = 0; hist2[tid] = 0; }
    __syncthreads();

    // ---- phase A: xs conv + closed-form t1 -> fired bitmasks
    unsigned int pca = 0, pcb = 0;           // packed hist1 counters (8-bit fields)
#pragma unroll
    for (int e = 0; e < 49; e++) {
        int g = e * TB + tid;
        int ci = g & 15, pos = g >> 4;
        int yy = pos / HW, xx = pos % HW;
        float acc = 0.f;
#pragma unroll
        for (int ky = 0; ky < 3; ky++) {
            int ys = yy + ky - 1;
            if (ys < 0 || ys >= HW) continue;
#pragma unroll
            for (int kx = 0; kx < 3; kx++) {
                int xsrc = xx + kx - 1;
                if (xsrc < 0 || xsrc >= HW) continue;
                acc = fmaf(wsc[ci * 9 + ky * 3 + kx], xst[ys * HW + xsrc], acc);
            }
        }
        int t1 = 8; float v = 0.f;
#pragma unroll
        for (int t = 0; t < TT; t++) {       // exact reference add order
            v += acc;
            if (t1 == 8 && v >= 1.0f) t1 = t;
        }
        if (t1 < 8) {
            atomicOr(&mask32[t1 * 392 + (pos >> 1)], (1u << ci) << ((pos & 1) * 16));
            if (t1 < 4) pca += 1u << (t1 * 8); else pcb += 1u << ((t1 - 4) * 8);
        }
    }
    if (half == 0) {
#pragma unroll
        for (int t = 0; t < TT; t++) {
            unsigned int c = ((t < 4 ? (pca >> (t * 8)) : (pcb >> ((t - 4) * 8))) & 255u);
            if (c) atomicAdd(&hist1[t], (int)c);
        }
    }
    __syncthreads();

    // ---- gather: per-thread positions, v2 in registers, no atomics/barriers
    unsigned int pc2a = 0, pc2b = 0;
    const unsigned short* m16 = (const unsigned short*)mask32;
    for (int own = 0; own < 4; own++) {
        int pos = tid + own * TB;
        if (pos >= NPIX) break;
        int py = pos / HW, px = pos % HW;
        float v2r[8] = {0.f, 0.f, 0.f, 0.f, 0.f, 0.f, 0.f, 0.f};
        unsigned int t2p = 0x88888888u;      // nibble 8 = never fired
        for (int t = 0; t < TT; t++) {
            const unsigned short* mt = m16 + t * NPIX;
#pragma unroll
            for (int k = 0; k < 9; k++) {
                int dy = k / 3 - 1, dx = k % 3 - 1;
                int qy = py + dy, qx = px + dx;
                if ((unsigned)qy >= HW || (unsigned)qx >= HW) continue;
                unsigned int m = mt[qy * HW + qx];
                while (m) {
                    int ci = __builtin_ctz(m); m &= m - 1;
                    const float* wrow = &wc[(ci * 9 + k) * 8];
                    float4 wa = *(const float4*)wrow;
                    float4 wb = *(const float4*)(wrow + 4);
                    v2r[0] += wa.x; v2r[1] += wa.y; v2r[2] += wa.z; v2r[3] += wa.w;
                    v2r[4] += wb.x; v2r[5] += wb.y; v2r[6] += wb.z; v2r[7] += wb.w;
                }
            }
#pragma unroll
            for (int c = 0; c < 8; c++) {
                if (((t2p >> (4 * c)) & 15u) == 8u && v2r[c] >= 1.0f) {
                    t2p = (t2p & ~(15u << (4 * c))) | ((unsigned)t << (4 * c));
                    if (t < 4) pc2a += 1u << (t * 8); else pc2b += 1u << ((t - 4) * 8);
                }
            }
        }
        t2w[pos] = t2p;
    }
#pragma unroll
    for (int t = 0; t < TT; t++) {
        unsigned int c = ((t < 4 ? (pc2a >> (t * 8)) : (pc2b >> ((t - 4) * 8))) & 255u);
        if (c) atomicAdd(&hist2[t], (int)c);
    }
    for (int i = tid; i < TT * TB; i += TB) facb[i] = 0.f;
    __syncthreads();

    // ---- first-spike pool: tq = min over 2x2 window of t2 nibbles
    for (int u = tid; u < 1568; u += TB) {   // u = c*196 + wy*14 + wx (c local)
        int c = u / 196, rem = u % 196;
        int wy = rem / 14, wx = rem % 14;
        int p0 = (wy * 2) * HW + wx * 2;
        unsigned int a = t2w[p0], b2 = t2w[p0 + 1];
        unsigned int d = t2w[p0 + HW], e2 = t2w[p0 + HW + 1];
        int sh = 4 * c;
        int m0 = (a >> sh) & 15, m1 = (b2 >> sh) & 15;
        int m2 = (d >> sh) & 15, m3 = (e2 >> sh) & 15;
        tq[u] = (unsigned char)min(min(m0, m1), min(m2, m3));
    }
    __syncthreads();

    // ---- FC1 bucket scan: unconditional loads, private LDS bucket slots
    {
        const int hh = tid >> 7;             // window half
        const int ii = tid & 127;            // fc neuron
        if (ii < NFC) {
            const float* wp = wT + (size_t)(co0 * 196 + hh * 784) * NFC + ii;
            for (int j = 0; j < 784; j++) {
                float w = wp[(size_t)j * NFC];      // pipelined (unconditional)
                int tv = tq[hh * 784 + j];          // broadcast LDS read
                if (tv < 8) facb[tv * TB + tid] += w;
            }
        }
    }
    __syncthreads();

    if (tid < NFC) {
#pragma unroll
        for (int t = 0; t < TT; t++)
            GLB_ADD(&vfcb[((size_t)b * TT + t) * NFC + tid],
                    facb[t * TB + tid] + facb[t * TB + 128 + tid]);
    }
    if (tid < TT) {
        if (half == 0) GLB_ADD(&fr_g[tid * 4 + 0], (float)hist1[tid]);
        GLB_ADD(&fr_g[tid * 4 + 1], (float)hist2[tid]);
    }
}

// ---------------------------------------------------------------------------
// Per-image: FC1 prefix -> t3, FC2 buckets, readout IF sim, latency score.
__global__ void snn_d(const float* __restrict__ vfcb, const float* __restrict__ w_fc2,
                      float* __restrict__ out, float* __restrict__ fr_g)
{
    __shared__ unsigned char t3L[NFC];
    __shared__ int hist3[TT], hist4[TT];
    const int tid = threadIdx.x;
    const int b = blockIdx.x;
    if (tid < TT) { hist3[tid] = 0; hist4[tid] = 0; }
    __syncthreads();
    if (tid < NFC) {
        float v = 0.f; int t3 = 8;
#pragma unroll
        for (int k = 0; k < TT; k++) {
            v += vfcb[((size_t)b * TT + k) * NFC + tid];
            if (t3 == 8 && v >= 1.0f) t3 = k;
        }
        t3L[tid] = (unsigned char)t3;
        if (t3 < 8) atomicAdd(&hist3[t3], 1);
    }
    __syncthreads();
    if (tid < NOUT) {
        float acc[TT] = {0.f, 0.f, 0.f, 0.f, 0.f, 0.f, 0.f, 0.f};
        for (int i = 0; i < NFC; i++) {
            float w = w_fc2[tid * NFC + i];  // unconditional load
            int tv = t3L[i];
#pragma unroll
            for (int k = 0; k < TT; k++) acc[k] += (tv == k) ? w : 0.f;
        }
        float vout = 0.f; int cnt = 0; float lat = 0.f;
#pragma unroll
        for (int t = 0; t < TT; t++) {
            vout += acc[t];
            if (vout >= 1.0f) { vout = 0.f; cnt++; atomicAdd(&hist4[t], 1); }
            if (cnt >= 1) lat += 1.f;
        }
        out[b * NOUT + tid] = lat * 0.125f;
    }
    __syncthreads();
    if (tid < TT) {
        GLB_ADD(&fr_g[tid * 4 + 2], (float)hist3[tid]);
        GLB_ADD(&fr_g[tid * 4 + 3], (float)hist4[tid]);
    }
}

// ---------------------------------------------------------------------------
__global__ void snn_finalize(const float* __restrict__ fr_g, float* __restrict__ out) {
    if (threadIdx.x == 0) {
        const float inv0 = 1.f / 6422528.f;   // B*16*28*28
        const float inv2 = 1.f / 51200.f;     // B*100
        const float inv3 = 1.f / 5120.f;      // B*10
        const float invs[4] = { inv0, inv0, inv2, inv3 };
        float reg = 0.f;
        for (int l = 0; l < 4; l++) {
            float mx = -INFINITY;
            for (int t = 0; t < TT; t++)
                mx = fmaxf(mx, fr_g[t * 4 + l] * invs[l]);
            reg += mx;
        }
        out[NIMG * NOUT] = reg;
    }
}

// ---------------------------------------------------------------------------
extern "C" void kernel_launch(void* const* d_in, const int* in_sizes, int n_in,
                              void* d_out, int out_size, void* d_ws, size_t ws_size,
                              hipStream_t stream) {
    const float* x       = (const float*)d_in[0];
    const float* w_sconv = (const float*)d_in[1];
    const float* w_conv  = (const float*)d_in[2];
    const float* w_fc1   = (const float*)d_in[3];
    const float* w_fc2   = (const float*)d_in[4];
    float* out = (float*)d_out;

    float* ws   = (float*)d_ws;
    float* wT   = ws;
    float* vfcb = ws + WT_FLOATS;
    float* fr_g = ws + FR_OFF;

    snn_init<<<1600, TB, 0, stream>>>(ws);
    snn_transpose<<<1225, TB, 0, stream>>>(w_fc1, wT);
    snn_main<<<NIMG * 2, TB, 0, stream>>>(x, w_sconv, w_conv, wT, vfcb, fr_g);
    snn_d<<<NIMG, 128, 0, stream>>>(vfcb, w_fc2, out, fr_g);
    snn_finalize<<<1, 64, 0, stream>>>(fr_g, out);
}

// Round 4
// 242.749 us; speedup vs baseline: 8.5039x; 1.2589x over previous
//
#include <hip/hip_runtime.h>

#define TB 256
#define NIMG 512
#define HW 28
#define NPIX 784
#define TT 8
#define NFC 100
#define NOUT 10

// workspace layout (floats): wT [3136][100], then fr_g [32]
#define WT_FLOATS 313600
#define GLB_ADD(p, v) __hip_atomic_fetch_add((p), (v), __ATOMIC_RELAXED, __HIP_MEMORY_SCOPE_AGENT)

// ---------------------------------------------------------------------------
// tiled transpose w_fc1 [100][3136] -> wT [3136][100]; block 0 zeroes fr_g
__global__ void snn_transpose(const float* __restrict__ w, float* __restrict__ wT,
                              float* __restrict__ fr_g) {
    __shared__ float tile[32 * 104];
    const int c0 = blockIdx.x * 32;          // 98 blocks x 32 cols (3136 exact)
    if (blockIdx.x == 0 && threadIdx.x < 32) fr_g[threadIdx.x] = 0.f;
    for (int idx = threadIdx.x; idx < 3200; idx += TB) {
        int r = idx >> 5, c = idx & 31;
        tile[c * 104 + r] = w[r * 3136 + c0 + c];
    }
    __syncthreads();
    for (int idx = threadIdx.x; idx < 3200; idx += TB) {
        int c = idx / 100, r = idx - c * 100;
        wT[(c0 + c) * 100 + r] = tile[c * 104 + r];
    }
}

// ---------------------------------------------------------------------------
// One block per image. Phase A: closed-form layer-1 spike times -> per-pos
// all-t bitmask (b128). Gather: register-resident v2 (16 co), barrier-free.
// Pool -> counting sort by first-spike t -> sorted-prefix FC1 -> FC2/readout.
__global__ __launch_bounds__(TB, 2)
void snn_main(const float* __restrict__ xg, const float* __restrict__ w_sconv,
              const float* __restrict__ w_conv, const float* __restrict__ w_fc2,
              const float* __restrict__ wT,
              float* __restrict__ out, float* __restrict__ fr_g)
{
    __shared__ float wc[144 * 20];           // row r=ci*9+k at wc[r*20], 16 co used
    __shared__ uint4 masks[NPIX];            // [pos]: 8 x u16 fired-ci masks (t0..t7)
    __shared__ unsigned int t2n[NPIX * 2];   // per pos: 16 co x 4-bit t2 (u64 as 2xu32)
    __shared__ unsigned char tqA[3136];      // pooled first-spike t (8=never); later t3L
    __shared__ unsigned short slist[3136];   // windows sorted by t
    __shared__ float prefixLDS[2 * TT * NFC];
    __shared__ float xst[NPIX];
    __shared__ float wsc[144];
    __shared__ int bcnt[9], bofs[9], bput[8];
    __shared__ int hist[32];                 // [layer*8 + t]

    const int tid = threadIdx.x;
    const int b = blockIdx.x;

    // ---- stage
    for (int i = tid; i < NPIX; i += TB) xst[i] = xg[b * NPIX + i];
    for (int i = tid; i < 144; i += TB) wsc[i] = w_sconv[i];
    for (int i = tid; i < 2304; i += TB) {
        int c = i & 15, r = i >> 4;          // r = ci*9 + k, c = co
        wc[r * 20 + c] = w_conv[c * 144 + r];
    }
    for (int i = tid; i < NPIX; i += TB) masks[i] = uint4{0u, 0u, 0u, 0u};
    if (tid < 32) hist[tid] = 0;
    if (tid < 9) bcnt[tid] = 0;
    __syncthreads();

    // ---- phase A: xs conv + closed-form t1 -> mask bits
    unsigned int pca = 0, pcb = 0;
#pragma unroll 1
    for (int e = 0; e < 49; e++) {
        int g = e * TB + tid;
        int ci = g & 15, pos = g >> 4;
        int yy = pos / HW, xx = pos % HW;
        float acc = 0.f;
#pragma unroll
        for (int ky = 0; ky < 3; ky++) {
            int ys = yy + ky - 1;
            if (ys < 0 || ys >= HW) continue;
#pragma unroll
            for (int kx = 0; kx < 3; kx++) {
                int xsrc = xx + kx - 1;
                if (xsrc < 0 || xsrc >= HW) continue;
                acc = fmaf(wsc[ci * 9 + ky * 3 + kx], xst[ys * HW + xsrc], acc);
            }
        }
        int t1 = 8; float v = 0.f;
#pragma unroll
        for (int t = 0; t < TT; t++) {       // exact reference add order
            v += acc;
            if (t1 == 8 && v >= 1.0f) t1 = t;
        }
        if (t1 < 8) {
            atomicOr(((unsigned int*)&masks[pos]) + (t1 >> 1),
                     (1u << ci) << ((t1 & 1) * 16));
            if (t1 < 4) pca += 1u << (t1 * 8); else pcb += 1u << ((t1 - 4) * 8);
        }
    }
#pragma unroll
    for (int t = 0; t < TT; t++) {
        unsigned int c = ((t < 4 ? (pca >> (t * 8)) : (pcb >> ((t - 4) * 8))) & 255u);
        if (c) atomicAdd(&hist[t], (int)c);
    }
    __syncthreads();

    // ---- gather: per-thread positions, v2[16] in registers, no atomics
    unsigned int pc2a = 0, pc2b = 0;
#pragma unroll 1
    for (int own = 0; own < 4; own++) {
        int pos = own * TB + tid;
        if (pos < NPIX) {
            int py = pos / HW, px = pos % HW;
            uint4 nb[9];
#pragma unroll
            for (int k = 0; k < 9; k++) {
                int qy = py + k / 3 - 1, qx = px + k % 3 - 1;
                if ((unsigned)qy < HW && (unsigned)qx < HW) nb[k] = masks[qy * HW + qx];
                else nb[k] = uint4{0u, 0u, 0u, 0u};
            }
            float v2r[16];
#pragma unroll
            for (int c = 0; c < 16; c++) v2r[c] = 0.f;
            unsigned int done = 0;
            unsigned int t2lo = 0x88888888u, t2hi = 0x88888888u;
#pragma unroll
            for (int t = 0; t < TT; t++) {
#pragma unroll
                for (int k = 0; k < 9; k++) {
                    unsigned int w32 = ((const unsigned int*)&nb[k])[t >> 1];
                    unsigned int m = (w32 >> ((t & 1) * 16)) & 0xffffu;
                    while (m) {
                        int ci = __builtin_ctz(m); m &= m - 1;
                        const float* wrow = &wc[(ci * 9 + k) * 20];
                        float4 a0 = *(const float4*)(wrow);
                        float4 a1 = *(const float4*)(wrow + 4);
                        float4 a2 = *(const float4*)(wrow + 8);
                        float4 a3 = *(const float4*)(wrow + 12);
                        v2r[0] += a0.x;  v2r[1] += a0.y;  v2r[2] += a0.z;  v2r[3] += a0.w;
                        v2r[4] += a1.x;  v2r[5] += a1.y;  v2r[6] += a1.z;  v2r[7] += a1.w;
                        v2r[8] += a2.x;  v2r[9] += a2.y;  v2r[10] += a2.z; v2r[11] += a2.w;
                        v2r[12] += a3.x; v2r[13] += a3.y; v2r[14] += a3.z; v2r[15] += a3.w;
                    }
                }
#pragma unroll
                for (int c = 0; c < 16; c++) {
                    if (!((done >> c) & 1u) && v2r[c] >= 1.0f) {
                        done |= 1u << c;
                        if (c < 8) t2lo = (t2lo & ~(15u << (4 * c))) | ((unsigned)t << (4 * c));
                        else       t2hi = (t2hi & ~(15u << (4 * (c - 8)))) | ((unsigned)t << (4 * (c - 8)));
                        if (t < 4) pc2a += 1u << (t * 8); else pc2b += 1u << ((t - 4) * 8);
                    }
                }
            }
            t2n[pos * 2] = t2lo;
            t2n[pos * 2 + 1] = t2hi;
        }
    }
#pragma unroll
    for (int t = 0; t < TT; t++) {
        unsigned int c = ((t < 4 ? (pc2a >> (t * 8)) : (pc2b >> ((t - 4) * 8))) & 255u);
        if (c) atomicAdd(&hist[8 + t], (int)c);
    }
    __syncthreads();

    // ---- first-spike pool + bucket histogram
    for (int u = tid; u < 3136; u += TB) {   // u = c*196 + wy*14 + wx
        int c = u / 196, rem = u - c * 196;
        int wy = rem / 14, wx = rem - wy * 14;
        int p0 = wy * 56 + wx * 2;
        int wsel = c >> 3, sh = (c & 7) * 4;
        int m0 = (t2n[p0 * 2 + wsel] >> sh) & 15;
        int m1 = (t2n[(p0 + 1) * 2 + wsel] >> sh) & 15;
        int m2 = (t2n[(p0 + HW) * 2 + wsel] >> sh) & 15;
        int m3 = (t2n[(p0 + HW + 1) * 2 + wsel] >> sh) & 15;
        int tqv = min(min(m0, m1), min(m2, m3));
        tqA[u] = (unsigned char)tqv;
        if (tqv < 8) atomicAdd(&bcnt[tqv], 1);
    }
    __syncthreads();
    if (tid == 0) {
        int s = 0;
#pragma unroll
        for (int t = 0; t < TT; t++) { bofs[t] = s; s += bcnt[t]; }
        bofs[8] = s;
    }
    __syncthreads();
    if (tid < 8) bput[tid] = bofs[tid];
    __syncthreads();
    for (int u = tid; u < 3136; u += TB) {
        int tqv = tqA[u];
        if (tqv < 8) { int j = atomicAdd(&bput[tqv], 1); slist[j] = (unsigned short)u; }
    }
    __syncthreads();

    // ---- FC1 sorted-prefix scan: pair hh takes every other element
    {
        const int hh = tid >> 7;             // wave pair 0/1
        const int ii = tid & 127;            // fc neuron
        float acc = 0.f;
#pragma unroll 1
        for (int t = 0; t < TT; t++) {
            const int lo = bofs[t], n = bofs[t + 1] - lo;
            if (ii < NFC) {
                const float* wbase = wT + ii;
#pragma unroll 4
                for (int q = hh; q < n; q += 2) {
                    int u = (int)slist[lo + q];
                    acc += wbase[(size_t)u * NFC];
                }
                prefixLDS[(hh * TT + t) * NFC + ii] = acc;
            }
        }
    }
    __syncthreads();

    // ---- t3 from combined prefixes
    if (tid < NFC) {
        int t3 = 8;
#pragma unroll
        for (int t = 0; t < TT; t++) {
            float v = prefixLDS[t * NFC + tid] + prefixLDS[(TT + t) * NFC + tid];
            if (t3 == 8 && v >= 1.0f) t3 = t;
        }
        tqA[tid] = (unsigned char)t3;        // reuse as t3L
        if (t3 < 8) atomicAdd(&hist[16 + t3], 1);
    }
    __syncthreads();

    // ---- FC2 buckets + readout IF sim + latency score
    if (tid < NOUT) {
        float acc8[TT] = {0.f, 0.f, 0.f, 0.f, 0.f, 0.f, 0.f, 0.f};
        for (int i = 0; i < NFC; i++) {
            float w = w_fc2[tid * NFC + i];
            int tv = tqA[i];
#pragma unroll
            for (int k = 0; k < TT; k++) acc8[k] += (tv == k) ? w : 0.f;
        }
        float vout = 0.f; int cnt = 0; float lat = 0.f;
#pragma unroll
        for (int t = 0; t < TT; t++) {
            vout += acc8[t];
            if (vout >= 1.0f) { vout = 0.f; cnt++; atomicAdd(&hist[24 + t], 1); }
            if (cnt >= 1) lat += 1.f;
        }
        out[b * NOUT + tid] = lat * 0.125f;
    }
    __syncthreads();
    if (tid < 32) {
        int h = hist[tid];
        if (h) GLB_ADD(&fr_g[(tid & 7) * 4 + (tid >> 3)], (float)h);
    }
}

// ---------------------------------------------------------------------------
__global__ void snn_finalize(const float* __restrict__ fr_g, float* __restrict__ out) {
    if (threadIdx.x == 0) {
        const float inv0 = 1.f / 6422528.f;   // B*16*28*28
        const float inv2 = 1.f / 51200.f;     // B*100
        const float inv3 = 1.f / 5120.f;      // B*10
        const float invs[4] = { inv0, inv0, inv2, inv3 };
        float reg = 0.f;
        for (int l = 0; l < 4; l++) {
            float mx = -INFINITY;
            for (int t = 0; t < TT; t++)
                mx = fmaxf(mx, fr_g[t * 4 + l] * invs[l]);
            reg += mx;
        }
        out[NIMG * NOUT] = reg;
    }
}

// ---------------------------------------------------------------------------
extern "C" void kernel_launch(void* const* d_in, const int* in_sizes, int n_in,
                              void* d_out, int out_size, void* d_ws, size_t ws_size,
                              hipStream_t stream) {
    const float* x       = (const float*)d_in[0];
    const float* w_sconv = (const float*)d_in[1];
    const float* w_conv  = (const float*)d_in[2];
    const float* w_fc1   = (const float*)d_in[3];
    const float* w_fc2   = (const float*)d_in[4];
    float* out = (float*)d_out;

    float* wT   = (float*)d_ws;
    float* fr_g = wT + WT_FLOATS;

    snn_transpose<<<98, TB, 0, stream>>>(w_fc1, wT, fr_g);
    snn_main<<<NIMG, TB, 0, stream>>>(x, w_sconv, w_conv, w_fc2, wT, out, fr_g);
    snn_finalize<<<1, 64, 0, stream>>>(fr_g, out);
}

// Round 5
// 233.370 us; speedup vs baseline: 8.8456x; 1.0402x over previous
//
#include <hip/hip_runtime.h>

#define TB 256
#define NIMG 512
#define HW 28
#define NPIX 784
#define TT 8
#define NFC 100
#define NOUT 10

// workspace layout (floats): wT [3136][100], fr_g[32], tcnt, done2
#define WT_FLOATS 313600
#define GLB_ADD(p, v) __hip_atomic_fetch_add((p), (v), __ATOMIC_RELAXED, __HIP_MEMORY_SCOPE_AGENT)

typedef float f4 __attribute__((ext_vector_type(4)));

// ---------------------------------------------------------------------------
// zero fr_g[32] + tcnt + done2 (runs every call; immune to ws poison/replay)
__global__ void snn_pre(unsigned int* p) {
    if (threadIdx.x < 34) p[threadIdx.x] = 0u;
}

// ---------------------------------------------------------------------------
// One block per image. Blocks 0..97 also transpose 32 columns of w_fc1 into
// wT first (release-counted; consumers acquire-spin before the FC scan).
__global__ __launch_bounds__(TB, 2)
void snn_main(const float* __restrict__ xg, const float* __restrict__ w_sconv,
              const float* __restrict__ w_conv, const float* __restrict__ w_fc1,
              const float* __restrict__ w_fc2, float* __restrict__ wT,
              float* __restrict__ out, float* __restrict__ fr_g,
              unsigned int* tcnt, unsigned int* done2)
{
    __shared__ float wc[2880];                  // row r=ci*9+k at wc[r*20], 16 co
    __shared__ unsigned char spanB[18816];      // masks[784]u4 + t2n[1568]u32; later prefixLDS
    __shared__ unsigned char tqA[3136];         // pooled first-spike t; later t3L
    __shared__ unsigned short slist[3136];      // windows sorted by t
    __shared__ float xst[NPIX];
    __shared__ float wsc[144];
    __shared__ int bcnt[9], bofs[9], bput[8];
    __shared__ int hist[32];                    // [layer*8 + t]
    __shared__ int lastflag;

    uint4* masks = (uint4*)spanB;               // [pos]: 8 u16 fired-ci masks
    unsigned int* t2n = (unsigned int*)(spanB + 12544); // [pos*2+w]: 16co x 4b t2
    float* prefixLDS = (float*)spanB;           // [stream][t][neuron] (post-pool)

    const int tid = threadIdx.x;
    const int b = blockIdx.x;

    // ---- cooperative transpose (blocks 0..97), write-coalesced
    if (b < 98) {
        const int c0 = b * 32;
        for (int idx = tid; idx < 3200; idx += TB) {
            int c = idx / 100, r = idx - 100 * c;
            wT[(c0 + c) * 100 + r] = w_fc1[r * 3136 + c0 + c];
        }
    }

    // ---- stage
    for (int i = tid; i < NPIX; i += TB) xst[i] = xg[b * NPIX + i];
    for (int i = tid; i < 144; i += TB) wsc[i] = w_sconv[i];
    for (int i = tid; i < 2304; i += TB) {
        int c = i & 15, r = i >> 4;             // r = ci*9 + k, c = co
        wc[r * 20 + c] = w_conv[c * 144 + r];
    }
    for (int i = tid; i < NPIX; i += TB) masks[i] = uint4{0u, 0u, 0u, 0u};
    if (tid < 32) hist[tid] = 0;
    if (tid < 9) bcnt[tid] = 0;
    __syncthreads();
    if (b < 98 && tid == 0)
        __hip_atomic_fetch_add(tcnt, 1u, __ATOMIC_RELEASE, __HIP_MEMORY_SCOPE_AGENT);

    // ---- phase A: xs conv + closed-form t1 -> mask bits
    unsigned int pca = 0, pcb = 0;
#pragma unroll 1
    for (int e = 0; e < 49; e++) {
        int g = e * TB + tid;
        int ci = g & 15, pos = g >> 4;
        int yy = pos / HW, xx = pos % HW;
        float acc = 0.f;
#pragma unroll
        for (int ky = 0; ky < 3; ky++) {
            int ys = yy + ky - 1;
            if (ys < 0 || ys >= HW) continue;
#pragma unroll
            for (int kx = 0; kx < 3; kx++) {
                int xsrc = xx + kx - 1;
                if (xsrc < 0 || xsrc >= HW) continue;
                acc = fmaf(wsc[ci * 9 + ky * 3 + kx], xst[ys * HW + xsrc], acc);
            }
        }
        int t1 = 8; float v = 0.f;
#pragma unroll
        for (int t = 0; t < TT; t++) {          // exact reference add order
            v += acc;
            if (t1 == 8 && v >= 1.0f) t1 = t;
        }
        if (t1 < 8) {
            atomicOr(((unsigned int*)&masks[pos]) + (t1 >> 1),
                     (1u << ci) << ((t1 & 1) * 16));
            if (t1 < 4) pca += 1u << (t1 * 8); else pcb += 1u << ((t1 - 4) * 8);
        }
    }
#pragma unroll
    for (int t = 0; t < TT; t++) {
        unsigned int c = ((t < 4 ? (pca >> (t * 8)) : (pcb >> ((t - 4) * 8))) & 255u);
        if (c) atomicAdd(&hist[t], (int)c);
    }
    __syncthreads();

    // ---- gather: per-thread positions, v2[16] in packed f4 regs
    unsigned int pc2a = 0, pc2b = 0;
#pragma unroll 1
    for (int own = 0; own < 4; own++) {
        int pos = own * TB + tid;
        if (pos < NPIX) {
            int py = pos / HW, px = pos % HW;
            uint4 nb[9];
#pragma unroll
            for (int k = 0; k < 9; k++) {
                int qy = py + k / 3 - 1, qx = px + k % 3 - 1;
                if ((unsigned)qy < HW && (unsigned)qx < HW) nb[k] = masks[qy * HW + qx];
                else nb[k] = uint4{0u, 0u, 0u, 0u};
            }
            f4 vv0 = {0.f, 0.f, 0.f, 0.f}, vv1 = vv0, vv2 = vv0, vv3 = vv0;
            unsigned int done = 0;
            unsigned int t2lo = 0x88888888u, t2hi = 0x88888888u;
#pragma unroll
            for (int t = 0; t < TT; t++) {
#pragma unroll
                for (int k = 0; k < 9; k++) {
                    unsigned int w32 = ((const unsigned int*)&nb[k])[t >> 1];
                    unsigned int m = (w32 >> ((t & 1) * 16)) & 0xffffu;
                    while (m) {
                        int ci = __builtin_ctz(m); m &= m - 1;
                        const f4* wrow = (const f4*)&wc[(ci * 9 + k) * 20];
                        vv0 += wrow[0]; vv1 += wrow[1];
                        vv2 += wrow[2]; vv3 += wrow[3];
                    }
                }
#pragma unroll
                for (int c = 0; c < 16; c++) {
                    float val = (c < 4) ? vv0[c & 3] : (c < 8) ? vv1[c & 3]
                              : (c < 12) ? vv2[c & 3] : vv3[c & 3];
                    if (!((done >> c) & 1u) && val >= 1.0f) {
                        done |= 1u << c;
                        if (c < 8) t2lo = (t2lo & ~(15u << (4 * c))) | ((unsigned)t << (4 * c));
                        else       t2hi = (t2hi & ~(15u << (4 * (c - 8)))) | ((unsigned)t << (4 * (c - 8)));
                        if (t < 4) pc2a += 1u << (t * 8); else pc2b += 1u << ((t - 4) * 8);
                    }
                }
            }
            t2n[pos * 2] = t2lo;
            t2n[pos * 2 + 1] = t2hi;
        }
    }
#pragma unroll
    for (int t = 0; t < TT; t++) {
        unsigned int c = ((t < 4 ? (pc2a >> (t * 8)) : (pc2b >> ((t - 4) * 8))) & 255u);
        if (c) atomicAdd(&hist[8 + t], (int)c);
    }
    __syncthreads();

    // ---- first-spike pool + bucket histogram
    for (int u = tid; u < 3136; u += TB) {      // u = c*196 + wy*14 + wx
        int c = u / 196, rem = u - c * 196;
        int wy = rem / 14, wx = rem - wy * 14;
        int p0 = wy * 56 + wx * 2;
        int wsel = c >> 3, sh = (c & 7) * 4;
        int m0 = (t2n[p0 * 2 + wsel] >> sh) & 15;
        int m1 = (t2n[(p0 + 1) * 2 + wsel] >> sh) & 15;
        int m2 = (t2n[(p0 + HW) * 2 + wsel] >> sh) & 15;
        int m3 = (t2n[(p0 + HW + 1) * 2 + wsel] >> sh) & 15;
        int tqv = min(min(m0, m1), min(m2, m3));
        tqA[u] = (unsigned char)tqv;
        if (tqv < 8) atomicAdd(&bcnt[tqv], 1);
    }
    __syncthreads();
    if (tid == 0) {
        int s = 0;
#pragma unroll
        for (int t = 0; t < TT; t++) { bofs[t] = s; s += bcnt[t]; }
        bofs[8] = s;
    }
    __syncthreads();
    if (tid < 8) bput[tid] = bofs[tid];
    __syncthreads();
    for (int u = tid; u < 3136; u += TB) {
        int tqv = tqA[u];
        if (tqv < 8) { int j = atomicAdd(&bput[tqv], 1); slist[j] = (unsigned short)u; }
    }

    // ---- wait for wT (long since done; ~0 spin)
    if (tid == 0) {
        while (__hip_atomic_load(tcnt, __ATOMIC_ACQUIRE, __HIP_MEMORY_SCOPE_AGENT) < 98u)
            __builtin_amdgcn_s_sleep(2);
    }
    __syncthreads();                            // also covers slist/t2n->prefix reuse

    // ---- FC1 sorted-prefix scan: 4 single-wave streams, unroll-4 loads
    {
        const int lane = tid & 63;
        const int w = tid >> 6;                 // stream 0..3, q = w (mod 4)
        const float* wA = wT + lane;
        const float* wB = wT + 64 + lane;
        float acc0 = 0.f, acc1 = 0.f;
#pragma unroll 1
        for (int t = 0; t < TT; t++) {
            const int lo = bofs[t];
            const int n = bofs[t + 1] - lo;
            int j = w;
            for (; j + 12 < n; j += 16) {
                int u0 = (int)slist[lo + j] * 100;
                int u1 = (int)slist[lo + j + 4] * 100;
                int u2 = (int)slist[lo + j + 8] * 100;
                int u3 = (int)slist[lo + j + 12] * 100;
                float a0 = wA[u0], a1 = wA[u1], a2 = wA[u2], a3 = wA[u3];
                if (lane < 36) {
                    float b0 = wB[u0], b1 = wB[u1], b2 = wB[u2], b3 = wB[u3];
                    acc1 += b0; acc1 += b1; acc1 += b2; acc1 += b3;
                }
                acc0 += a0; acc0 += a1; acc0 += a2; acc0 += a3;
            }
            for (; j < n; j += 4) {
                int u0 = (int)slist[lo + j] * 100;
                acc0 += wA[u0];
                if (lane < 36) acc1 += wB[u0];
            }
            prefixLDS[(w * TT + t) * NFC + lane] = acc0;
            if (lane < 36) prefixLDS[(w * TT + t) * NFC + 64 + lane] = acc1;
        }
    }
    __syncthreads();

    // ---- t3 from combined stream prefixes
    if (tid < NFC) {
        int t3 = 8;
#pragma unroll
        for (int t = 0; t < TT; t++) {
            float v = prefixLDS[t * NFC + tid]
                    + prefixLDS[(TT + t) * NFC + tid]
                    + prefixLDS[(2 * TT + t) * NFC + tid]
                    + prefixLDS[(3 * TT + t) * NFC + tid];
            if (t3 == 8 && v >= 1.0f) t3 = t;
        }
        tqA[tid] = (unsigned char)t3;           // reuse as t3L
        if (t3 < 8) atomicAdd(&hist[16 + t3], 1);
    }
    __syncthreads();

    // ---- FC2 buckets + readout IF sim + latency score
    if (tid < NOUT) {
        float acc8[TT] = {0.f, 0.f, 0.f, 0.f, 0.f, 0.f, 0.f, 0.f};
        for (int i = 0; i < NFC; i++) {
            float w = w_fc2[tid * NFC + i];
            int tv = tqA[i];
#pragma unroll
            for (int k = 0; k < TT; k++) acc8[k] += (tv == k) ? w : 0.f;
        }
        float vout = 0.f; int cnt = 0; float lat = 0.f;
#pragma unroll
        for (int t = 0; t < TT; t++) {
            vout += acc8[t];
            if (vout >= 1.0f) { vout = 0.f; cnt++; atomicAdd(&hist[24 + t], 1); }
            if (cnt >= 1) lat += 1.f;
        }
        out[b * NOUT + tid] = lat * 0.125f;
    }
    __syncthreads();
    if (tid < 32) {
        int h = hist[tid];
        if (h) GLB_ADD(&fr_g[(tid & 7) * 4 + (tid >> 3)], (float)h);
    }
    __syncthreads();

    // ---- last-block-done fused finalize
    if (tid == 0) {
        unsigned int old = __hip_atomic_fetch_add(done2, 1u, __ATOMIC_ACQ_REL,
                                                  __HIP_MEMORY_SCOPE_AGENT);
        lastflag = (old == (unsigned)(NIMG - 1));
    }
    __syncthreads();
    if (lastflag && tid == 0) {
        const float inv0 = 1.f / 6422528.f;     // B*16*28*28
        const float inv2 = 1.f / 51200.f;       // B*100
        const float inv3 = 1.f / 5120.f;        // B*10
        const float invs[4] = { inv0, inv0, inv2, inv3 };
        float reg = 0.f;
        for (int l = 0; l < 4; l++) {
            float mx = -INFINITY;
            for (int t = 0; t < TT; t++) {
                float v = __hip_atomic_load(&fr_g[t * 4 + l], __ATOMIC_RELAXED,
                                            __HIP_MEMORY_SCOPE_AGENT);
                mx = fmaxf(mx, v * invs[l]);
            }
            reg += mx;
        }
        out[NIMG * NOUT] = reg;
    }
}

// ---------------------------------------------------------------------------
extern "C" void kernel_launch(void* const* d_in, const int* in_sizes, int n_in,
                              void* d_out, int out_size, void* d_ws, size_t ws_size,
                              hipStream_t stream) {
    const float* x       = (const float*)d_in[0];
    const float* w_sconv = (const float*)d_in[1];
    const float* w_conv  = (const float*)d_in[2];
    const float* w_fc1   = (const float*)d_in[3];
    const float* w_fc2   = (const float*)d_in[4];
    float* out = (float*)d_out;

    float* wT           = (float*)d_ws;
    float* fr_g         = wT + WT_FLOATS;
    unsigned int* tcnt  = (unsigned int*)(fr_g + 32);
    unsigned int* done2 = tcnt + 1;

    snn_pre<<<1, 64, 0, stream>>>((unsigned int*)fr_g);
    snn_main<<<NIMG, TB, 0, stream>>>(x, w_sconv, w_conv, w_fc1, w_fc2, wT,
                                      out, fr_g, tcnt, done2);
}

// Round 6
// 222.951 us; speedup vs baseline: 9.2590x; 1.0467x over previous
//
#include <hip/hip_runtime.h>

#define TB 512
#define NIMG 512
#define HW 28
#define NPIX 784
#define TT 8
#define NFC 100
#define NOUT 10
#define MAGIC 0x5C5C5C5Cu

// workspace layout: wT [3136][100] floats, then u32 ctrl[]:
//   ctrl[0..97]   = transpose-done flags (MAGIC when slice written)
//   ctrl[98..129] = fr_g[32] (float)
//   ctrl[130]     = done2 counter
//   ctrl[131]     = fr_ready flag
#define WT_FLOATS 313600
#define GLB_ADD(p, v) __hip_atomic_fetch_add((p), (v), __ATOMIC_RELAXED, __HIP_MEMORY_SCOPE_AGENT)

typedef float f4 __attribute__((ext_vector_type(4)));

// ---------------------------------------------------------------------------
// Single fused kernel. One block (512 thr) per image; blocks 0..97 also
// transpose 32 columns of w_fc1 into wT (flag-published); block 0 zeroes the
// global accumulators; last finished block computes reg_loss.
__global__ __launch_bounds__(TB, 4)
void snn_main(const float* __restrict__ xg, const float* __restrict__ w_sconv,
              const float* __restrict__ w_conv, const float* __restrict__ w_fc1,
              const float* __restrict__ w_fc2, float* __restrict__ wT,
              float* __restrict__ out, unsigned int* __restrict__ ctrl)
{
    __shared__ float wc[2880];                  // row r=ci*9+k at wc[r*20], 16 co
    __shared__ unsigned char spanB[25600];      // masks+t2n; later prefixLDS[8][8][100]
    __shared__ unsigned char tqA[3136];         // pooled first-spike t; later t3L
    __shared__ unsigned short slist[3136];      // windows sorted by t
    __shared__ float xst[NPIX];
    __shared__ float wsc[144];
    __shared__ int bcnt[9], bofs[9], bput[8];
    __shared__ int hist[32];                    // [layer*8 + t]
    __shared__ int lastflag;

    uint4* masks = (uint4*)spanB;               // [pos]: 8 u16 fired-ci masks
    unsigned int* t2n = (unsigned int*)(spanB + 12544); // [pos*2+w]: 16co x 4b t2
    float* prefixLDS = (float*)spanB;           // [stream][t][neuron] (post-pool)

    unsigned int* tflags = ctrl;
    float* fr_g = (float*)(ctrl + 98);
    unsigned int* done2 = ctrl + 130;
    unsigned int* fr_ready = ctrl + 131;

    const int tid = threadIdx.x;
    const int b = blockIdx.x;

    // ---- cooperative transpose (blocks 0..97) + block-0 accumulator zeroing
    if (b < 98) {
        const int c0 = b * 32;
        for (int idx = tid; idx < 3200; idx += TB) {
            int c = idx / 100, r = idx - 100 * c;
            wT[(c0 + c) * 100 + r] = w_fc1[r * 3136 + c0 + c];
        }
    }
    if (b == 0 && tid < 33) ctrl[98 + tid] = 0u;   // fr_g[32] + done2

    // ---- stage
    for (int i = tid; i < NPIX; i += TB) xst[i] = xg[b * NPIX + i];
    for (int i = tid; i < 144; i += TB) wsc[i] = w_sconv[i];
    for (int i = tid; i < 2304; i += TB) {
        int c = i & 15, r = i >> 4;             // r = ci*9 + k, c = co
        wc[r * 20 + c] = w_conv[c * 144 + r];
    }
    for (int i = tid; i < NPIX; i += TB) masks[i] = uint4{0u, 0u, 0u, 0u};
    if (tid < 32) hist[tid] = 0;
    if (tid < 9) bcnt[tid] = 0;
    if (b < 98) __threadfence();                // publish wT/ctrl writes
    __syncthreads();
    if (b < 98 && tid == 0) {
        __hip_atomic_store(&tflags[b], MAGIC, __ATOMIC_RELEASE, __HIP_MEMORY_SCOPE_AGENT);
        if (b == 0)
            __hip_atomic_store(fr_ready, MAGIC, __ATOMIC_RELEASE, __HIP_MEMORY_SCOPE_AGENT);
    }

    // ---- phase A: xs conv + closed-form t1 -> mask bits
    unsigned int pca = 0, pcb = 0;
#pragma unroll 1
    for (int e = 0; e < 25; e++) {
        int g = e * TB + tid;
        if (g < 12544) {
            int ci = g & 15, pos = g >> 4;
            int yy = pos / HW, xx = pos % HW;
            float acc = 0.f;
#pragma unroll
            for (int ky = 0; ky < 3; ky++) {
                int ys = yy + ky - 1;
                if (ys < 0 || ys >= HW) continue;
#pragma unroll
                for (int kx = 0; kx < 3; kx++) {
                    int xsrc = xx + kx - 1;
                    if (xsrc < 0 || xsrc >= HW) continue;
                    acc = fmaf(wsc[ci * 9 + ky * 3 + kx], xst[ys * HW + xsrc], acc);
                }
            }
            int t1 = 8; float v = 0.f;
#pragma unroll
            for (int t = 0; t < TT; t++) {      // exact reference add order
                v += acc;
                if (t1 == 8 && v >= 1.0f) t1 = t;
            }
            if (t1 < 8) {
                atomicOr(((unsigned int*)&masks[pos]) + (t1 >> 1),
                         (1u << ci) << ((t1 & 1) * 16));
                if (t1 < 4) pca += 1u << (t1 * 8); else pcb += 1u << ((t1 - 4) * 8);
            }
        }
    }
#pragma unroll
    for (int t = 0; t < TT; t++) {
        unsigned int c = ((t < 4 ? (pca >> (t * 8)) : (pcb >> ((t - 4) * 8))) & 255u);
        if (c) atomicAdd(&hist[t], (int)c);
    }
    __syncthreads();

    // ---- gather: per-thread positions, v2[16] in packed f4 regs
    unsigned int pc2a = 0, pc2b = 0;
#pragma unroll 1
    for (int own = 0; own < 2; own++) {
        int pos = own * TB + tid;
        if (pos < NPIX) {
            int py = pos / HW, px = pos % HW;
            uint4 nb[9];
#pragma unroll
            for (int k = 0; k < 9; k++) {
                int qy = py + k / 3 - 1, qx = px + k % 3 - 1;
                if ((unsigned)qy < HW && (unsigned)qx < HW) nb[k] = masks[qy * HW + qx];
                else nb[k] = uint4{0u, 0u, 0u, 0u};
            }
            f4 vv0 = {0.f, 0.f, 0.f, 0.f}, vv1 = vv0, vv2 = vv0, vv3 = vv0;
            unsigned int done = 0;
            unsigned int t2lo = 0x88888888u, t2hi = 0x88888888u;
#pragma unroll
            for (int t = 0; t < TT; t++) {
#pragma unroll
                for (int k = 0; k < 9; k++) {
                    unsigned int w32 = ((const unsigned int*)&nb[k])[t >> 1];
                    unsigned int m = (w32 >> ((t & 1) * 16)) & 0xffffu;
                    while (m) {
                        int ci = __builtin_ctz(m); m &= m - 1;
                        const f4* wrow = (const f4*)&wc[(ci * 9 + k) * 20];
                        vv0 += wrow[0]; vv1 += wrow[1];
                        vv2 += wrow[2]; vv3 += wrow[3];
                    }
                }
#pragma unroll
                for (int c = 0; c < 16; c++) {
                    float val = (c < 4) ? vv0[c & 3] : (c < 8) ? vv1[c & 3]
                              : (c < 12) ? vv2[c & 3] : vv3[c & 3];
                    if (!((done >> c) & 1u) && val >= 1.0f) {
                        done |= 1u << c;
                        if (c < 8) t2lo = (t2lo & ~(15u << (4 * c))) | ((unsigned)t << (4 * c));
                        else       t2hi = (t2hi & ~(15u << (4 * (c - 8)))) | ((unsigned)t << (4 * (c - 8)));
                        if (t < 4) pc2a += 1u << (t * 8); else pc2b += 1u << ((t - 4) * 8);
                    }
                }
            }
            t2n[pos * 2] = t2lo;
            t2n[pos * 2 + 1] = t2hi;
        }
    }
#pragma unroll
    for (int t = 0; t < TT; t++) {
        unsigned int c = ((t < 4 ? (pc2a >> (t * 8)) : (pc2b >> ((t - 4) * 8))) & 255u);
        if (c) atomicAdd(&hist[8 + t], (int)c);
    }
    __syncthreads();

    // ---- first-spike pool + bucket histogram
    for (int u = tid; u < 3136; u += TB) {      // u = c*196 + wy*14 + wx
        int c = u / 196, rem = u - c * 196;
        int wy = rem / 14, wx = rem - wy * 14;
        int p0 = wy * 56 + wx * 2;
        int wsel = c >> 3, sh = (c & 7) * 4;
        int m0 = (t2n[p0 * 2 + wsel] >> sh) & 15;
        int m1 = (t2n[(p0 + 1) * 2 + wsel] >> sh) & 15;
        int m2 = (t2n[(p0 + HW) * 2 + wsel] >> sh) & 15;
        int m3 = (t2n[(p0 + HW + 1) * 2 + wsel] >> sh) & 15;
        int tqv = min(min(m0, m1), min(m2, m3));
        tqA[u] = (unsigned char)tqv;
        if (tqv < 8) atomicAdd(&bcnt[tqv], 1);
    }
    __syncthreads();
    if (tid == 0) {
        int s = 0;
#pragma unroll
        for (int t = 0; t < TT; t++) { bofs[t] = s; s += bcnt[t]; }
        bofs[8] = s;
    }
    __syncthreads();
    if (tid < 8) bput[tid] = bofs[tid];
    __syncthreads();
    for (int u = tid; u < 3136; u += TB) {
        int tqv = tqA[u];
        if (tqv < 8) { int j = atomicAdd(&bput[tqv], 1); slist[j] = (unsigned short)u; }
    }

    // ---- wait for wT slices (long since done; ~single pass)
    if (tid < 98) {
        while (__hip_atomic_load(&tflags[tid], __ATOMIC_ACQUIRE,
                                 __HIP_MEMORY_SCOPE_AGENT) != MAGIC)
            __builtin_amdgcn_s_sleep(2);
    }
    __syncthreads();                            // also covers slist/t2n->prefix reuse

    // ---- FC1 sorted-prefix scan: 8 single-wave streams, unroll-4 loads
    {
        const int lane = tid & 63;
        const int w = tid >> 6;                 // stream 0..7, q = w (mod 8)
        const float* wA = wT + lane;
        const float* wB = wT + 64 + lane;
        float acc0 = 0.f, acc1 = 0.f;
#pragma unroll 1
        for (int t = 0; t < TT; t++) {
            const int lo = bofs[t];
            const int n = bofs[t + 1] - lo;
            int j = w;
            for (; j + 24 < n; j += 32) {
                int u0 = (int)slist[lo + j] * 100;
                int u1 = (int)slist[lo + j + 8] * 100;
                int u2 = (int)slist[lo + j + 16] * 100;
                int u3 = (int)slist[lo + j + 24] * 100;
                float a0 = wA[u0], a1 = wA[u1], a2 = wA[u2], a3 = wA[u3];
                if (lane < 36) {
                    float b0 = wB[u0], b1 = wB[u1], b2 = wB[u2], b3 = wB[u3];
                    acc1 += b0; acc1 += b1; acc1 += b2; acc1 += b3;
                }
                acc0 += a0; acc0 += a1; acc0 += a2; acc0 += a3;
            }
            for (; j < n; j += 8) {
                int u0 = (int)slist[lo + j] * 100;
                acc0 += wA[u0];
                if (lane < 36) acc1 += wB[u0];
            }
            prefixLDS[(w * TT + t) * NFC + lane] = acc0;
            if (lane < 36) prefixLDS[(w * TT + t) * NFC + 64 + lane] = acc1;
        }
    }
    __syncthreads();

    // ---- t3 from combined stream prefixes
    if (tid < NFC) {
        int t3 = 8;
#pragma unroll
        for (int t = 0; t < TT; t++) {
            float v = 0.f;
#pragma unroll
            for (int w = 0; w < 8; w++) v += prefixLDS[(w * TT + t) * NFC + tid];
            if (t3 == 8 && v >= 1.0f) t3 = t;
        }
        tqA[tid] = (unsigned char)t3;           // reuse as t3L
        if (t3 < 8) atomicAdd(&hist[16 + t3], 1);
    }
    __syncthreads();

    // ---- FC2 buckets + readout IF sim + latency score
    if (tid < NOUT) {
        float acc8[TT] = {0.f, 0.f, 0.f, 0.f, 0.f, 0.f, 0.f, 0.f};
        for (int i = 0; i < NFC; i++) {
            float w = w_fc2[tid * NFC + i];
            int tv = tqA[i];
#pragma unroll
            for (int k = 0; k < TT; k++) acc8[k] += (tv == k) ? w : 0.f;
        }
        float vout = 0.f; int cnt = 0; float lat = 0.f;
#pragma unroll
        for (int t = 0; t < TT; t++) {
            vout += acc8[t];
            if (vout >= 1.0f) { vout = 0.f; cnt++; atomicAdd(&hist[24 + t], 1); }
            if (cnt >= 1) lat += 1.f;
        }
        out[b * NOUT + tid] = lat * 0.125f;
    }
    __syncthreads();

    // ---- wait for fr_g zeroing (block 0; long since done), flush histograms
    if (tid == 0) {
        while (__hip_atomic_load(fr_ready, __ATOMIC_ACQUIRE,
                                 __HIP_MEMORY_SCOPE_AGENT) != MAGIC)
            __builtin_amdgcn_s_sleep(2);
    }
    __syncthreads();
    if (tid < 32) {
        int h = hist[tid];
        if (h) GLB_ADD(&fr_g[(tid & 7) * 4 + (tid >> 3)], (float)h);
    }
    __syncthreads();

    // ---- last-block-done fused finalize
    if (tid == 0) {
        unsigned int old = __hip_atomic_fetch_add(done2, 1u, __ATOMIC_ACQ_REL,
                                                  __HIP_MEMORY_SCOPE_AGENT);
        lastflag = (old == (unsigned)(NIMG - 1));
    }
    __syncthreads();
    if (lastflag && tid == 0) {
        const float inv0 = 1.f / 6422528.f;     // B*16*28*28
        const float inv2 = 1.f / 51200.f;       // B*100
        const float inv3 = 1.f / 5120.f;        // B*10
        const float invs[4] = { inv0, inv0, inv2, inv3 };
        float reg = 0.f;
        for (int l = 0; l < 4; l++) {
            float mx = -INFINITY;
            for (int t = 0; t < TT; t++) {
                float v = __hip_atomic_load(&fr_g[t * 4 + l], __ATOMIC_RELAXED,
                                            __HIP_MEMORY_SCOPE_AGENT);
                mx = fmaxf(mx, v * invs[l]);
            }
            reg += mx;
        }
        out[NIMG * NOUT] = reg;
    }
}

// ---------------------------------------------------------------------------
extern "C" void kernel_launch(void* const* d_in, const int* in_sizes, int n_in,
                              void* d_out, int out_size, void* d_ws, size_t ws_size,
                              hipStream_t stream) {
    const float* x       = (const float*)d_in[0];
    const float* w_sconv = (const float*)d_in[1];
    const float* w_conv  = (const float*)d_in[2];
    const float* w_fc1   = (const float*)d_in[3];
    const float* w_fc2   = (const float*)d_in[4];
    float* out = (float*)d_out;

    float* wT          = (float*)d_ws;
    unsigned int* ctrl = (unsigned int*)(wT + WT_FLOATS);

    snn_main<<<NIMG, TB, 0, stream>>>(x, w_sconv, w_conv, w_fc1, w_fc2, wT,
                                      out, ctrl);
}

// Round 7
// 199.344 us; speedup vs baseline: 10.3555x; 1.1184x over previous
//
#include <hip/hip_runtime.h>

#define TB 512
#define NIMG 512
#define HW 28
#define NPIX 784
#define TT 8
#define NFC 100
#define NOUT 10
#define MAGIC 0x5C5C5C5Cu

// workspace layout: wT [3136][100] floats, then u32 ctrl[]:
//   ctrl[0..97]   = transpose-done flags (MAGIC when slice written)
//   ctrl[98..129] = fr_g[32] (float)
//   ctrl[130]     = done2 counter
//   ctrl[131]     = fr_ready flag
#define WT_FLOATS 313600
#define GLB_ADD(p, v) __hip_atomic_fetch_add((p), (v), __ATOMIC_RELAXED, __HIP_MEMORY_SCOPE_AGENT)

typedef float f4 __attribute__((ext_vector_type(4)));

// ---------------------------------------------------------------------------
// Single fused kernel. One block (512 thr) per image; blocks 0..97 also
// transpose 32 columns of w_fc1 into wT (flag-published); block 0 zeroes the
// global accumulators; last finished block computes reg_loss.
__global__ __launch_bounds__(TB, 4)
void snn_main(const float* __restrict__ xg, const float* __restrict__ w_sconv,
              const float* __restrict__ w_conv, const float* __restrict__ w_fc1,
              const float* __restrict__ w_fc2, float* __restrict__ wT,
              float* __restrict__ out, unsigned int* __restrict__ ctrl)
{
    __shared__ float wc[2880];                  // row r=ci*9+k at wc[r*20], 16 co
    __shared__ unsigned char spanB[25600];      // mask_t[8][784]u16 + t2n; later prefixLDS
    __shared__ unsigned short rowOr[TT * HW];   // per (t,row) OR of masks
    __shared__ unsigned char tqA[3136];         // pooled first-spike t; later t3L
    __shared__ unsigned short slist[3136];      // windows sorted by t
    __shared__ float xst[NPIX];
    __shared__ float wsc[144];
    __shared__ int bcnt[9], bofs[9], bput[8];
    __shared__ int hist[32];                    // [layer*8 + t]
    __shared__ int lastflag;

    unsigned short* mask_t = (unsigned short*)spanB;        // [t*784 + pos]
    unsigned int* mask32 = (unsigned int*)spanB;            // u32 view for atomicOr
    unsigned int* t2n = (unsigned int*)(spanB + 12544);     // [pos*2+w]: 16co x 4b
    float* prefixLDS = (float*)spanB;                       // [stream][t][neuron]

    unsigned int* tflags = ctrl;
    float* fr_g = (float*)(ctrl + 98);
    unsigned int* done2 = ctrl + 130;
    unsigned int* fr_ready = ctrl + 131;

    const int tid = threadIdx.x;
    const int b = blockIdx.x;

    // ---- cooperative transpose (blocks 0..97) + block-0 accumulator zeroing
    if (b < 98) {
        const int c0 = b * 32;
        for (int idx = tid; idx < 3200; idx += TB) {
            int c = idx / 100, r = idx - 100 * c;
            wT[(c0 + c) * 100 + r] = w_fc1[r * 3136 + c0 + c];
        }
    }
    if (b == 0 && tid < 33) ctrl[98 + tid] = 0u;   // fr_g[32] + done2

    // ---- stage
    for (int i = tid; i < NPIX; i += TB) xst[i] = xg[b * NPIX + i];
    for (int i = tid; i < 144; i += TB) wsc[i] = w_sconv[i];
    for (int i = tid; i < 2304; i += TB) {
        int c = i & 15, r = i >> 4;             // r = ci*9 + k, c = co
        wc[r * 20 + c] = w_conv[c * 144 + r];
    }
    for (int i = tid; i < 3136; i += TB) mask32[i] = 0u;    // 8*784 u16
    if (tid < 32) hist[tid] = 0;
    if (tid < 9) bcnt[tid] = 0;
    if (b < 98) __threadfence();                // publish wT/ctrl writes
    __syncthreads();
    if (b < 98 && tid == 0) {
        __hip_atomic_store(&tflags[b], MAGIC, __ATOMIC_RELEASE, __HIP_MEMORY_SCOPE_AGENT);
        if (b == 0)
            __hip_atomic_store(fr_ready, MAGIC, __ATOMIC_RELEASE, __HIP_MEMORY_SCOPE_AGENT);
    }

    // ---- phase A: xs conv + closed-form t1 -> mask bits
    unsigned int pca = 0, pcb = 0;
#pragma unroll 1
    for (int e = 0; e < 25; e++) {
        int g = e * TB + tid;
        if (g < 12544) {
            int ci = g & 15, pos = g >> 4;
            int yy = pos / HW, xx = pos % HW;
            float acc = 0.f;
#pragma unroll
            for (int ky = 0; ky < 3; ky++) {
                int ys = yy + ky - 1;
                if (ys < 0 || ys >= HW) continue;
#pragma unroll
                for (int kx = 0; kx < 3; kx++) {
                    int xsrc = xx + kx - 1;
                    if (xsrc < 0 || xsrc >= HW) continue;
                    acc = fmaf(wsc[ci * 9 + ky * 3 + kx], xst[ys * HW + xsrc], acc);
                }
            }
            int t1 = 8; float v = 0.f;
#pragma unroll
            for (int t = 0; t < TT; t++) {      // exact reference add order
                v += acc;
                if (t1 == 8 && v >= 1.0f) t1 = t;
            }
            if (t1 < 8) {
                int lin = t1 * NPIX + pos;
                atomicOr(&mask32[lin >> 1], (1u << ci) << ((lin & 1) * 16));
                if (t1 < 4) pca += 1u << (t1 * 8); else pcb += 1u << ((t1 - 4) * 8);
            }
        }
    }
#pragma unroll
    for (int t = 0; t < TT; t++) {
        unsigned int c = ((t < 4 ? (pca >> (t * 8)) : (pcb >> ((t - 4) * 8))) & 255u);
        if (c) atomicAdd(&hist[t], (int)c);
    }
    __syncthreads();

    // ---- row-union summary (skip table)
    for (int i = tid; i < TT * HW; i += TB) {   // i = t*28 + y
        const unsigned short* mr = mask_t + (i / HW) * NPIX + (i % HW) * HW;
        unsigned int o = 0;
#pragma unroll
        for (int x = 0; x < HW; x++) o |= mr[x];
        rowOr[i] = (unsigned short)o;
    }
    __syncthreads();

    // ---- gather: per-thread positions, v2[16] in packed f4 regs, LDS masks
    unsigned int pc2a = 0, pc2b = 0;
#pragma unroll 1
    for (int own = 0; own < 2; own++) {
        int pos = own * TB + tid;
        if (pos < NPIX) {
            int py = pos / HW, px = pos - py * HW;
            f4 vv0 = {0.f, 0.f, 0.f, 0.f}, vv1 = vv0, vv2 = vv0, vv3 = vv0;
            unsigned int done = 0;
            unsigned int t2lo = 0x88888888u, t2hi = 0x88888888u;
#pragma unroll 1
            for (int t = 0; t < TT; t++) {
                const unsigned short* ro = rowOr + t * HW;
                unsigned int un = ro[py];
                if (py > 0) un |= ro[py - 1];
                if (py < HW - 1) un |= ro[py + 1];
                if (!un) continue;              // no adds at t -> no new crossing
                const unsigned short* mt = mask_t + t * NPIX;
#pragma unroll
                for (int k = 0; k < 9; k++) {
                    int qy = py + k / 3 - 1, qx = px + k % 3 - 1;
                    if ((unsigned)qy >= HW || (unsigned)qx >= HW) continue;
                    unsigned int m = mt[qy * HW + qx];
                    while (m) {
                        int ci = __builtin_ctz(m); m &= m - 1;
                        const f4* wrow = (const f4*)&wc[(ci * 9 + k) * 20];
                        vv0 += wrow[0]; vv1 += wrow[1];
                        vv2 += wrow[2]; vv3 += wrow[3];
                    }
                }
                unsigned int fired = 0;
#pragma unroll
                for (int c = 0; c < 16; c++) {
                    float val = (c < 4) ? vv0[c & 3] : (c < 8) ? vv1[c & 3]
                              : (c < 12) ? vv2[c & 3] : vv3[c & 3];
                    fired |= (val >= 1.0f) ? (1u << c) : 0u;
                }
                unsigned int newf = fired & ~done;
                done |= newf;
                if (newf) {
                    int cnt = __builtin_popcount(newf);
                    if (t < 4) pc2a += (unsigned)cnt << (t * 8);
                    else       pc2b += (unsigned)cnt << ((t - 4) * 8);
                    while (newf) {
                        int c = __builtin_ctz(newf); newf &= newf - 1;
                        if (c < 8) t2lo = (t2lo & ~(15u << (4 * c))) | ((unsigned)t << (4 * c));
                        else       t2hi = (t2hi & ~(15u << (4 * (c - 8)))) | ((unsigned)t << (4 * (c - 8)));
                    }
                }
                if (done == 0xffffu) break;     // all co fired; rest irrelevant
            }
            t2n[pos * 2] = t2lo;
            t2n[pos * 2 + 1] = t2hi;
        }
    }
#pragma unroll
    for (int t = 0; t < TT; t++) {
        unsigned int c = ((t < 4 ? (pc2a >> (t * 8)) : (pc2b >> ((t - 4) * 8))) & 255u);
        if (c) atomicAdd(&hist[8 + t], (int)c);
    }
    __syncthreads();

    // ---- first-spike pool + bucket histogram
    for (int u = tid; u < 3136; u += TB) {      // u = c*196 + wy*14 + wx
        int c = u / 196, rem = u - c * 196;
        int wy = rem / 14, wx = rem - wy * 14;
        int p0 = wy * 56 + wx * 2;
        int wsel = c >> 3, sh = (c & 7) * 4;
        int m0 = (t2n[p0 * 2 + wsel] >> sh) & 15;
        int m1 = (t2n[(p0 + 1) * 2 + wsel] >> sh) & 15;
        int m2 = (t2n[(p0 + HW) * 2 + wsel] >> sh) & 15;
        int m3 = (t2n[(p0 + HW + 1) * 2 + wsel] >> sh) & 15;
        int tqv = min(min(m0, m1), min(m2, m3));
        tqA[u] = (unsigned char)tqv;
        if (tqv < 8) atomicAdd(&bcnt[tqv], 1);
    }
    __syncthreads();
    if (tid == 0) {
        int s = 0;
#pragma unroll
        for (int t = 0; t < TT; t++) { bofs[t] = s; s += bcnt[t]; }
        bofs[8] = s;
    }
    __syncthreads();
    if (tid < 8) bput[tid] = bofs[tid];
    __syncthreads();
    for (int u = tid; u < 3136; u += TB) {
        int tqv = tqA[u];
        if (tqv < 8) { int j = atomicAdd(&bput[tqv], 1); slist[j] = (unsigned short)u; }
    }

    // ---- wait for wT slices (long since done; ~single pass)
    if (tid < 98) {
        while (__hip_atomic_load(&tflags[tid], __ATOMIC_ACQUIRE,
                                 __HIP_MEMORY_SCOPE_AGENT) != MAGIC)
            __builtin_amdgcn_s_sleep(2);
    }
    __syncthreads();                            // also covers t2n -> prefix reuse

    // ---- FC1 sorted-prefix scan: 8 single-wave streams, unroll-4 loads
    {
        const int lane = tid & 63;
        const int w = tid >> 6;                 // stream 0..7, q = w (mod 8)
        const float* wA = wT + lane;
        const float* wB = wT + 64 + lane;
        float acc0 = 0.f, acc1 = 0.f;
#pragma unroll 1
        for (int t = 0; t < TT; t++) {
            const int lo = bofs[t];
            const int n = bofs[t + 1] - lo;
            int j = w;
            for (; j + 24 < n; j += 32) {
                int u0 = (int)slist[lo + j] * 100;
                int u1 = (int)slist[lo + j + 8] * 100;
                int u2 = (int)slist[lo + j + 16] * 100;
                int u3 = (int)slist[lo + j + 24] * 100;
                float a0 = wA[u0], a1 = wA[u1], a2 = wA[u2], a3 = wA[u3];
                if (lane < 36) {
                    float b0 = wB[u0], b1 = wB[u1], b2 = wB[u2], b3 = wB[u3];
                    acc1 += b0; acc1 += b1; acc1 += b2; acc1 += b3;
                }
                acc0 += a0; acc0 += a1; acc0 += a2; acc0 += a3;
            }
            for (; j < n; j += 8) {
                int u0 = (int)slist[lo + j] * 100;
                acc0 += wA[u0];
                if (lane < 36) acc1 += wB[u0];
            }
            prefixLDS[(w * TT + t) * NFC + lane] = acc0;
            if (lane < 36) prefixLDS[(w * TT + t) * NFC + 64 + lane] = acc1;
        }
    }
    __syncthreads();

    // ---- t3 from combined stream prefixes
    if (tid < NFC) {
        int t3 = 8;
#pragma unroll
        for (int t = 0; t < TT; t++) {
            float v = 0.f;
#pragma unroll
            for (int w = 0; w < 8; w++) v += prefixLDS[(w * TT + t) * NFC + tid];
            if (t3 == 8 && v >= 1.0f) t3 = t;
        }
        tqA[tid] = (unsigned char)t3;           // reuse as t3L
        if (t3 < 8) atomicAdd(&hist[16 + t3], 1);
    }
    __syncthreads();

    // ---- FC2 buckets + readout IF sim + latency score
    if (tid < NOUT) {
        float acc8[TT] = {0.f, 0.f, 0.f, 0.f, 0.f, 0.f, 0.f, 0.f};
        for (int i = 0; i < NFC; i++) {
            float w = w_fc2[tid * NFC + i];
            int tv = tqA[i];
#pragma unroll
            for (int k = 0; k < TT; k++) acc8[k] += (tv == k) ? w : 0.f;
        }
        float vout = 0.f; int cnt = 0; float lat = 0.f;
#pragma unroll
        for (int t = 0; t < TT; t++) {
            vout += acc8[t];
            if (vout >= 1.0f) { vout = 0.f; cnt++; atomicAdd(&hist[24 + t], 1); }
            if (cnt >= 1) lat += 1.f;
        }
        out[b * NOUT + tid] = lat * 0.125f;
    }
    __syncthreads();

    // ---- wait for fr_g zeroing (block 0; long since done), flush histograms
    if (tid == 0) {
        while (__hip_atomic_load(fr_ready, __ATOMIC_ACQUIRE,
                                 __HIP_MEMORY_SCOPE_AGENT) != MAGIC)
            __builtin_amdgcn_s_sleep(2);
    }
    __syncthreads();
    if (tid < 32) {
        int h = hist[tid];
        if (h) GLB_ADD(&fr_g[(tid & 7) * 4 + (tid >> 3)], (float)h);
    }
    __syncthreads();

    // ---- last-block-done fused finalize
    if (tid == 0) {
        unsigned int old = __hip_atomic_fetch_add(done2, 1u, __ATOMIC_ACQ_REL,
                                                  __HIP_MEMORY_SCOPE_AGENT);
        lastflag = (old == (unsigned)(NIMG - 1));
    }
    __syncthreads();
    if (lastflag && tid == 0) {
        const float inv0 = 1.f / 6422528.f;     // B*16*28*28
        const float inv2 = 1.f / 51200.f;       // B*100
        const float inv3 = 1.f / 5120.f;        // B*10
        const float invs[4] = { inv0, inv0, inv2, inv3 };
        float reg = 0.f;
        for (int l = 0; l < 4; l++) {
            float mx = -INFINITY;
            for (int t = 0; t < TT; t++) {
                float v = __hip_atomic_load(&fr_g[t * 4 + l], __ATOMIC_RELAXED,
                                            __HIP_MEMORY_SCOPE_AGENT);
                mx = fmaxf(mx, v * invs[l]);
            }
            reg += mx;
        }
        out[NIMG * NOUT] = reg;
    }
}

// ---------------------------------------------------------------------------
extern "C" void kernel_launch(void* const* d_in, const int* in_sizes, int n_in,
                              void* d_out, int out_size, void* d_ws, size_t ws_size,
                              hipStream_t stream) {
    const float* x       = (const float*)d_in[0];
    const float* w_sconv = (const float*)d_in[1];
    const float* w_conv  = (const float*)d_in[2];
    const float* w_fc1   = (const float*)d_in[3];
    const float* w_fc2   = (const float*)d_in[4];
    float* out = (float*)d_out;

    float* wT          = (float*)d_ws;
    unsigned int* ctrl = (unsigned int*)(wT + WT_FLOATS);

    snn_main<<<NIMG, TB, 0, stream>>>(x, w_sconv, w_conv, w_fc1, w_fc2, wT,
                                      out, ctrl);
}